// Round 1
// baseline (396.026 us; speedup 1.0000x reference)
//
#include <hip/hip_runtime.h>

#define N_NODES 50000
#define N_EDGES 800000
#define D_IN 128
#define HH 4
#define FF 16
#define HF 64  // HH*FF

// ---------------- init: zero out + denom, set segmax keys to INT_MIN ----------------
__global__ __launch_bounds__(256) void init_kernel(float* __restrict__ out,
                                                   float* __restrict__ denom,
                                                   int* __restrict__ segmax) {
    int idx = blockIdx.x * 256 + threadIdx.x;
    if (idx < N_NODES * HF) out[idx] = 0.0f;
    if (idx < N_NODES * HH) {
        denom[idx] = 0.0f;
        segmax[idx] = (int)0x80000000;  // below the key of -inf
    }
}

// ---------------- GEMM: ft[N,64] = feat[N,128] @ W[128,64] ----------------
// Block = 256 threads (4 waves). W staged in LDS (32 KB). 64 rows per block,
// wave handles one row at a time, lane = output column.
__global__ __launch_bounds__(256) void gemm_kernel(const float* __restrict__ feat,
                                                   const float* __restrict__ W,
                                                   float* __restrict__ ft) {
    __shared__ float Wl[D_IN * HF];          // 32 KB
    __shared__ float frow[4][D_IN];          // 2 KB, per-wave staging

    const float4* W4 = (const float4*)W;
    float4* Wl4 = (float4*)Wl;
    for (int i = threadIdx.x; i < D_IN * HF / 4; i += 256) Wl4[i] = W4[i];
    __syncthreads();

    const int wave = threadIdx.x >> 6;
    const int lane = threadIdx.x & 63;
    const int row0 = blockIdx.x * 64;

    for (int r = wave; r < 64; r += 4) {
        int row = row0 + r;
        if (row >= N_NODES) break;
        const float* fr = feat + (size_t)row * D_IN;
        // wave-cooperative stage of the feat row (2 floats per lane)
        frow[wave][lane] = fr[lane];
        frow[wave][lane + 64] = fr[lane + 64];
        // wave-synchronous: LDS write->read within one wave needs no barrier
        float acc = 0.0f;
#pragma unroll
        for (int k = 0; k < D_IN; ++k) {
            acc += frow[wave][k] * Wl[k * HF + lane];
        }
        ft[(size_t)row * HF + lane] = acc;
    }
}

// float -> monotone signed-int key
__device__ __forceinline__ int f2key(float f) {
    int i = __float_as_int(f);
    return i >= 0 ? i : (i ^ 0x7FFFFFFF);
}
__device__ __forceinline__ float key2f(int k) {
    return k >= 0 ? __int_as_float(k) : __int_as_float(k ^ 0x7FFFFFFF);
}

// ---------------- scores: e[E,H] = dot(ft[src],ft[dst]) per head / 4; segmax ----------------
__global__ __launch_bounds__(256) void scores_kernel(const float* __restrict__ ft,
                                                     const int* __restrict__ src,
                                                     const int* __restrict__ dst,
                                                     float* __restrict__ e,
                                                     int* __restrict__ segmax) {
    int idx = blockIdx.x * 256 + threadIdx.x;  // (edge, head)
    if (idx >= N_EDGES * HH) return;
    int edge = idx >> 2;
    int h = idx & 3;
    int s = src[edge];
    int d = dst[edge];
    const float4* a = (const float4*)(ft + (size_t)s * HF + h * FF);
    const float4* b = (const float4*)(ft + (size_t)d * HF + h * FF);
    float acc = 0.0f;
#pragma unroll
    for (int i = 0; i < 4; ++i) {
        float4 x = a[i], y = b[i];
        acc += x.x * y.x + x.y * y.y + x.z * y.z + x.w * y.w;
    }
    acc *= 0.25f;  // 1/sqrt(16)
    e[idx] = acc;
    atomicMax(&segmax[d * HH + h], f2key(acc));
}

// ---------------- exp + denom ----------------
__global__ __launch_bounds__(256) void exp_kernel(const int* __restrict__ dst,
                                                  const int* __restrict__ segmax,
                                                  float* __restrict__ e,  // in: e, out: ex
                                                  float* __restrict__ denom) {
    int idx = blockIdx.x * 256 + threadIdx.x;
    if (idx >= N_EDGES * HH) return;
    int edge = idx >> 2;
    int h = idx & 3;
    int d = dst[edge];
    float m = key2f(segmax[d * HH + h]);
    float ex = expf(e[idx] - m);
    e[idx] = ex;
    atomicAdd(&denom[d * HH + h], ex);
}

// ---------------- scatter: out[dst] += ft[src] * (ex/denom[dst]) ----------------
// One wave per edge; lane l <-> (h = l/16, f = l%16).
__global__ __launch_bounds__(256) void scatter_kernel(const float* __restrict__ ft,
                                                      const int* __restrict__ src,
                                                      const int* __restrict__ dst,
                                                      const float* __restrict__ ex,
                                                      const float* __restrict__ denom,
                                                      float* __restrict__ out) {
    int gid = blockIdx.x * 256 + threadIdx.x;
    int edge = gid >> 6;
    if (edge >= N_EDGES) return;
    int l = gid & 63;
    int h = l >> 4;
    int s = src[edge];
    int d = dst[edge];
    float sa = ex[edge * HH + h] / denom[d * HH + h];
    float v = ft[(size_t)s * HF + l] * sa;
    atomicAdd(&out[(size_t)d * HF + l], v);
}

extern "C" void kernel_launch(void* const* d_in, const int* in_sizes, int n_in,
                              void* d_out, int out_size, void* d_ws, size_t ws_size,
                              hipStream_t stream) {
    const float* feat = (const float*)d_in[0];
    const float* W = (const float*)d_in[1];
    const int* src = (const int*)d_in[2];
    const int* dst = (const int*)d_in[3];
    float* out = (float*)d_out;

    // workspace layout (floats)
    float* ft = (float*)d_ws;                       // N*64   = 3.2M
    float* e = ft + (size_t)N_NODES * HF;           // E*4    = 3.2M
    int* segmax = (int*)(e + (size_t)N_EDGES * HH); // N*4    = 200K
    float* denom = (float*)(segmax + N_NODES * HH); // N*4    = 200K

    // init (out zeroed, segmax to -inf-key, denom zero)
    {
        int total = N_NODES * HF;
        init_kernel<<<(total + 255) / 256, 256, 0, stream>>>(out, denom, segmax);
    }
    // GEMM
    gemm_kernel<<<(N_NODES + 63) / 64, 256, 0, stream>>>(feat, W, ft);
    // scores + segment max
    scores_kernel<<<(N_EDGES * HH + 255) / 256, 256, 0, stream>>>(ft, src, dst, e, segmax);
    // exp + denom
    exp_kernel<<<(N_EDGES * HH + 255) / 256, 256, 0, stream>>>(dst, segmax, e, denom);
    // weighted scatter
    scatter_kernel<<<((size_t)N_EDGES * 64 + 255) / 256, 256, 0, stream>>>(ft, src, dst, e, denom, out);
}

// Round 2
// 306.600 us; speedup vs baseline: 1.2917x; 1.2917x over previous
//
#include <hip/hip_runtime.h>

#define N_NODES 50000
#define N_EDGES 800000
#define D_IN 128
#define HH 4
#define FF 16
#define HF 64  // HH*FF
#define NBLK_SCAN ((N_NODES + 255) / 256)  // 196

// ---------------- zero the degree histogram ----------------
__global__ __launch_bounds__(256) void zero_cnt_kernel(int* __restrict__ cnt) {
    int i = blockIdx.x * 256 + threadIdx.x;
    if (i < N_NODES) cnt[i] = 0;
}

// ---------------- GEMM: ft[N,64] = feat[N,128] @ W[128,64] ----------------
__global__ __launch_bounds__(256) void gemm_kernel(const float* __restrict__ feat,
                                                   const float* __restrict__ W,
                                                   float* __restrict__ ft) {
    __shared__ float Wl[D_IN * HF];          // 32 KB
    __shared__ float frow[4][D_IN];          // 2 KB

    const float4* W4 = (const float4*)W;
    float4* Wl4 = (float4*)Wl;
    for (int i = threadIdx.x; i < D_IN * HF / 4; i += 256) Wl4[i] = W4[i];
    __syncthreads();

    const int wave = threadIdx.x >> 6;
    const int lane = threadIdx.x & 63;
    const int row0 = blockIdx.x * 64;

    for (int r = wave; r < 64; r += 4) {
        int row = row0 + r;
        if (row >= N_NODES) break;
        const float* fr = feat + (size_t)row * D_IN;
        frow[wave][lane] = fr[lane];
        frow[wave][lane + 64] = fr[lane + 64];
        float acc = 0.0f;
#pragma unroll
        for (int k = 0; k < D_IN; ++k) {
            acc += frow[wave][k] * Wl[k * HF + lane];
        }
        ft[(size_t)row * HF + lane] = acc;
    }
}

// ---------------- histogram of dst ----------------
__global__ __launch_bounds__(256) void hist_kernel(const int* __restrict__ dst,
                                                   int* __restrict__ cnt) {
    int i = blockIdx.x * 256 + threadIdx.x;
    if (i < N_EDGES) atomicAdd(&cnt[dst[i]], 1);
}

// ---------------- scan stage 1: per-256-block exclusive scan ----------------
__global__ __launch_bounds__(256) void scan1_kernel(const int* __restrict__ cnt,
                                                    int* __restrict__ row_ptr,
                                                    int* __restrict__ block_sums) {
    __shared__ int s[256];
    int tid = threadIdx.x;
    int i = blockIdx.x * 256 + tid;
    int val = (i < N_NODES) ? cnt[i] : 0;
    s[tid] = val;
    __syncthreads();
#pragma unroll
    for (int off = 1; off < 256; off <<= 1) {
        int t = (tid >= off) ? s[tid - off] : 0;
        __syncthreads();
        s[tid] += t;
        __syncthreads();
    }
    if (i < N_NODES) row_ptr[i] = s[tid] - val;  // exclusive
    if (tid == 255) block_sums[blockIdx.x] = s[255];
}

// ---------------- scan stage 2: scan the 196 block sums ----------------
__global__ __launch_bounds__(256) void scan2_kernel(int* __restrict__ block_sums) {
    __shared__ int s[256];
    int tid = threadIdx.x;
    int val = (tid < NBLK_SCAN) ? block_sums[tid] : 0;
    s[tid] = val;
    __syncthreads();
#pragma unroll
    for (int off = 1; off < 256; off <<= 1) {
        int t = (tid >= off) ? s[tid - off] : 0;
        __syncthreads();
        s[tid] += t;
        __syncthreads();
    }
    if (tid < NBLK_SCAN) block_sums[tid] = s[tid] - val;  // exclusive
}

// ---------------- scan stage 3: add block offsets; init cursor ----------------
__global__ __launch_bounds__(256) void scan3_kernel(int* __restrict__ row_ptr,
                                                    const int* __restrict__ block_sums,
                                                    int* __restrict__ cursor) {
    int tid = threadIdx.x;
    int i = blockIdx.x * 256 + tid;
    if (i < N_NODES) {
        int v = row_ptr[i] + block_sums[blockIdx.x];
        row_ptr[i] = v;
        cursor[i] = v;
    }
    if (blockIdx.x == 0 && tid == 0) {
        // not strictly needed (total is a constant) but keep CSR well-formed
        row_ptr[N_NODES] = N_EDGES;
    }
}

// ---------------- group: scatter src ids into dst-grouped order ----------------
__global__ __launch_bounds__(256) void group_kernel(const int* __restrict__ src,
                                                    const int* __restrict__ dst,
                                                    int* __restrict__ cursor,
                                                    int* __restrict__ src_grouped) {
    int i = blockIdx.x * 256 + threadIdx.x;
    if (i >= N_EDGES) return;
    int d = dst[i];
    int pos = atomicAdd(&cursor[d], 1);
    src_grouped[pos] = src[i];
}

// ---------------- fused gather: one wave per destination node ----------------
// lane l <-> (h = l/16, f = l%16). Online softmax in registers, no atomics.
__global__ __launch_bounds__(256) void gather_kernel(const float* __restrict__ ft,
                                                     const int* __restrict__ row_ptr,
                                                     const int* __restrict__ src_grouped,
                                                     float* __restrict__ out) {
    int gid = blockIdx.x * 256 + threadIdx.x;
    int node = gid >> 6;
    if (node >= N_NODES) return;
    int lane = gid & 63;

    int beg = row_ptr[node];
    int end = row_ptr[node + 1];

    float ftd = ft[(size_t)node * HF + lane];

    float m = -3.0e38f;   // running max (replicated across the 16 lanes of a head)
    float l = 0.0f;       // running denom
    float acc = 0.0f;     // running weighted sum of ft[src][lane]

    for (int i = beg; i < end; ++i) {
        int s = src_grouped[i];
        float v = ft[(size_t)s * HF + lane];
        // per-head dot product: reduce over the 16 lanes of this head
        float p = ftd * v;
        p += __shfl_xor(p, 1, 64);
        p += __shfl_xor(p, 2, 64);
        p += __shfl_xor(p, 4, 64);
        p += __shfl_xor(p, 8, 64);
        float e = p * 0.25f;  // 1/sqrt(16)
        // online softmax update
        float nm = fmaxf(m, e);
        float a = __expf(m - nm);   // 0 on first edge (underflow)
        float w = __expf(e - nm);
        acc = acc * a + w * v;
        l = l * a + w;
        m = nm;
    }

    float r = (end > beg) ? acc / l : 0.0f;
    out[(size_t)node * HF + lane] = r;
}

extern "C" void kernel_launch(void* const* d_in, const int* in_sizes, int n_in,
                              void* d_out, int out_size, void* d_ws, size_t ws_size,
                              hipStream_t stream) {
    const float* feat = (const float*)d_in[0];
    const float* W = (const float*)d_in[1];
    const int* src = (const int*)d_in[2];
    const int* dst = (const int*)d_in[3];
    float* out = (float*)d_out;

    // workspace layout
    float* ft = (float*)d_ws;                          // N*64 floats
    int* cnt = (int*)(ft + (size_t)N_NODES * HF);      // N ints
    int* row_ptr = cnt + N_NODES;                      // N+1 ints
    int* cursor = row_ptr + N_NODES + 1;               // N ints
    int* src_grouped = cursor + N_NODES;               // E ints
    int* block_sums = src_grouped + N_EDGES;           // NBLK_SCAN ints

    zero_cnt_kernel<<<NBLK_SCAN, 256, 0, stream>>>(cnt);
    gemm_kernel<<<(N_NODES + 63) / 64, 256, 0, stream>>>(feat, W, ft);
    hist_kernel<<<(N_EDGES + 255) / 256, 256, 0, stream>>>(dst, cnt);
    scan1_kernel<<<NBLK_SCAN, 256, 0, stream>>>(cnt, row_ptr, block_sums);
    scan2_kernel<<<1, 256, 0, stream>>>(block_sums);
    scan3_kernel<<<NBLK_SCAN, 256, 0, stream>>>(row_ptr, block_sums, cursor);
    group_kernel<<<(N_EDGES + 255) / 256, 256, 0, stream>>>(src, dst, cursor, src_grouped);
    gather_kernel<<<(N_NODES * 64 + 255) / 256, 256, 0, stream>>>(ft, row_ptr, src_grouped, out);
}

// Round 3
// 229.071 us; speedup vs baseline: 1.7288x; 1.3384x over previous
//
#include <hip/hip_runtime.h>

#define N_NODES 50000
#define N_EDGES 800000
#define D_IN 128
#define HH 4
#define FF 16
#define HF 64  // HH*FF
#define NBLK_SCAN ((N_NODES + 255) / 256)  // 196
#define GEMM_BLOCKS ((N_NODES + 63) / 64)  // 782

// ---------------- GEMM (+fused dst histogram) ----------------
// ft[N,64] = feat[N,128] @ W[128,64].
// Each lane (=output col) holds its entire W column in 128 VGPRs.
// feat rows stream through a per-wave LDS buffer, read as float4 broadcasts.
__global__ __launch_bounds__(256) void gemm_hist_kernel(const float* __restrict__ feat,
                                                        const float* __restrict__ W,
                                                        const int* __restrict__ dst,
                                                        float* __restrict__ ft,
                                                        int* __restrict__ cnt) {
    __shared__ float Wl[D_IN * HF];          // 32 KB
    __shared__ float frow[4][D_IN];          // 2 KB, per-wave staging

    const float4* W4 = (const float4*)W;
    float4* Wl4 = (float4*)Wl;
    for (int i = threadIdx.x; i < D_IN * HF / 4; i += 256) Wl4[i] = W4[i];
    __syncthreads();

    const int wave = __builtin_amdgcn_readfirstlane(threadIdx.x >> 6);
    const int lane = threadIdx.x & 63;

    // W column -> registers (128 VGPRs); Wl[k*64+lane] is stride-1 across lanes.
    float w[D_IN];
#pragma unroll
    for (int k = 0; k < D_IN; ++k) w[k] = Wl[k * HF + lane];

    int row0 = blockIdx.x * 64 + wave * 16;
    int nrows = N_NODES - row0;
    if (nrows > 16) nrows = 16;

    float a0 = 0.0f, a1 = 0.0f;
    if (nrows > 0) {
        const float* fr = feat + (size_t)row0 * D_IN;
        a0 = fr[lane];
        a1 = fr[lane + 64];
    }
    for (int r = 0; r < nrows; ++r) {
        // wave-synchronous LDS staging (same-wave write->read, no barrier needed)
        frow[wave][lane] = a0;
        frow[wave][lane + 64] = a1;
        // prefetch next row while computing this one
        if (r + 1 < nrows) {
            const float* fr = feat + (size_t)(row0 + r + 1) * D_IN;
            a0 = fr[lane];
            a1 = fr[lane + 64];
        }
        float acc = 0.0f;
#pragma unroll
        for (int k4 = 0; k4 < D_IN / 4; ++k4) {
            float4 f = *(const float4*)&frow[wave][k4 * 4];  // uniform-addr broadcast
            acc = fmaf(f.x, w[4 * k4 + 0], acc);
            acc = fmaf(f.y, w[4 * k4 + 1], acc);
            acc = fmaf(f.z, w[4 * k4 + 2], acc);
            acc = fmaf(f.w, w[4 * k4 + 3], acc);
        }
        ft[(size_t)(row0 + r) * HF + lane] = acc;
    }

    // fused histogram of dst (cnt pre-zeroed by memset)
    int tid = blockIdx.x * 256 + threadIdx.x;
    for (int i = tid; i < N_EDGES; i += GEMM_BLOCKS * 256) {
        atomicAdd(&cnt[dst[i]], 1);
    }
}

// ---------------- scan stage 1: per-256-block exclusive scan ----------------
__global__ __launch_bounds__(256) void scan1_kernel(const int* __restrict__ cnt,
                                                    int* __restrict__ row_ptr,
                                                    int* __restrict__ block_sums) {
    __shared__ int s[256];
    int tid = threadIdx.x;
    int i = blockIdx.x * 256 + tid;
    int val = (i < N_NODES) ? cnt[i] : 0;
    s[tid] = val;
    __syncthreads();
#pragma unroll
    for (int off = 1; off < 256; off <<= 1) {
        int t = (tid >= off) ? s[tid - off] : 0;
        __syncthreads();
        s[tid] += t;
        __syncthreads();
    }
    if (i < N_NODES) row_ptr[i] = s[tid] - val;  // exclusive
    if (tid == 255) block_sums[blockIdx.x] = s[255];
}

// ---------------- scan stage 2: scan the 196 block sums ----------------
__global__ __launch_bounds__(256) void scan2_kernel(int* __restrict__ block_sums) {
    __shared__ int s[256];
    int tid = threadIdx.x;
    int val = (tid < NBLK_SCAN) ? block_sums[tid] : 0;
    s[tid] = val;
    __syncthreads();
#pragma unroll
    for (int off = 1; off < 256; off <<= 1) {
        int t = (tid >= off) ? s[tid - off] : 0;
        __syncthreads();
        s[tid] += t;
        __syncthreads();
    }
    if (tid < NBLK_SCAN) block_sums[tid] = s[tid] - val;  // exclusive
}

// ---------------- scan stage 3: add block offsets; init cursor ----------------
__global__ __launch_bounds__(256) void scan3_kernel(int* __restrict__ row_ptr,
                                                    const int* __restrict__ block_sums,
                                                    int* __restrict__ cursor) {
    int tid = threadIdx.x;
    int i = blockIdx.x * 256 + tid;
    if (i < N_NODES) {
        int v = row_ptr[i] + block_sums[blockIdx.x];
        row_ptr[i] = v;
        cursor[i] = v;
    }
    if (blockIdx.x == 0 && tid == 0) row_ptr[N_NODES] = N_EDGES;
}

// ---------------- group: scatter src ids into dst-grouped order ----------------
__global__ __launch_bounds__(256) void group_kernel(const int* __restrict__ src,
                                                    const int* __restrict__ dst,
                                                    int* __restrict__ cursor,
                                                    int* __restrict__ src_grouped) {
    int i4 = (blockIdx.x * 256 + threadIdx.x) * 4;
    if (i4 >= N_EDGES) return;  // N_EDGES % 4 == 0, whole int4 in-bounds
    int4 s4 = *(const int4*)&src[i4];
    int4 d4 = *(const int4*)&dst[i4];
    int pos;
    pos = atomicAdd(&cursor[d4.x], 1); src_grouped[pos] = s4.x;
    pos = atomicAdd(&cursor[d4.y], 1); src_grouped[pos] = s4.y;
    pos = atomicAdd(&cursor[d4.z], 1); src_grouped[pos] = s4.z;
    pos = atomicAdd(&cursor[d4.w], 1); src_grouped[pos] = s4.w;
}

// ---------------- fused gather: one wave per destination node ----------------
// lane l <-> (h = l/16, f = l%16). Softmax WITHOUT max-subtraction (scores are
// bounded: |e| <= |ft_s||ft_d|/4 ~ 16, exp() safely inside fp32 range), so the
// per-edge work has no serial rescale chain. 4-edge ILP unroll.
__global__ __launch_bounds__(256) void gather_kernel(const float* __restrict__ ft,
                                                     const int* __restrict__ row_ptr,
                                                     const int* __restrict__ src_grouped,
                                                     float* __restrict__ out) {
    int node = __builtin_amdgcn_readfirstlane(blockIdx.x * 4 + (threadIdx.x >> 6));
    int lane = threadIdx.x & 63;

    int beg = row_ptr[node];
    int end = row_ptr[node + 1];

    float ftd = ft[(size_t)node * HF + lane];
    float acc = 0.0f, l = 0.0f;

    int i = beg;
    for (; i + 4 <= end; i += 4) {
        int s0 = src_grouped[i + 0];
        int s1 = src_grouped[i + 1];
        int s2 = src_grouped[i + 2];
        int s3 = src_grouped[i + 3];
        float v0 = ft[(size_t)s0 * HF + lane];
        float v1 = ft[(size_t)s1 * HF + lane];
        float v2 = ft[(size_t)s2 * HF + lane];
        float v3 = ft[(size_t)s3 * HF + lane];
        float p0 = ftd * v0, p1 = ftd * v1, p2 = ftd * v2, p3 = ftd * v3;
        p0 += __shfl_xor(p0, 1, 64); p1 += __shfl_xor(p1, 1, 64);
        p2 += __shfl_xor(p2, 1, 64); p3 += __shfl_xor(p3, 1, 64);
        p0 += __shfl_xor(p0, 2, 64); p1 += __shfl_xor(p1, 2, 64);
        p2 += __shfl_xor(p2, 2, 64); p3 += __shfl_xor(p3, 2, 64);
        p0 += __shfl_xor(p0, 4, 64); p1 += __shfl_xor(p1, 4, 64);
        p2 += __shfl_xor(p2, 4, 64); p3 += __shfl_xor(p3, 4, 64);
        p0 += __shfl_xor(p0, 8, 64); p1 += __shfl_xor(p1, 8, 64);
        p2 += __shfl_xor(p2, 8, 64); p3 += __shfl_xor(p3, 8, 64);
        float w0 = __expf(p0 * 0.25f);
        float w1 = __expf(p1 * 0.25f);
        float w2 = __expf(p2 * 0.25f);
        float w3 = __expf(p3 * 0.25f);
        acc = fmaf(w0, v0, acc);
        acc = fmaf(w1, v1, acc);
        acc = fmaf(w2, v2, acc);
        acc = fmaf(w3, v3, acc);
        l += (w0 + w1) + (w2 + w3);
    }
    for (; i < end; ++i) {
        int s = src_grouped[i];
        float v = ft[(size_t)s * HF + lane];
        float p = ftd * v;
        p += __shfl_xor(p, 1, 64);
        p += __shfl_xor(p, 2, 64);
        p += __shfl_xor(p, 4, 64);
        p += __shfl_xor(p, 8, 64);
        float w = __expf(p * 0.25f);
        acc = fmaf(w, v, acc);
        l += w;
    }

    out[(size_t)node * HF + lane] = (end > beg) ? acc / l : 0.0f;
}

extern "C" void kernel_launch(void* const* d_in, const int* in_sizes, int n_in,
                              void* d_out, int out_size, void* d_ws, size_t ws_size,
                              hipStream_t stream) {
    const float* feat = (const float*)d_in[0];
    const float* W = (const float*)d_in[1];
    const int* src = (const int*)d_in[2];
    const int* dst = (const int*)d_in[3];
    float* out = (float*)d_out;

    // workspace layout
    float* ft = (float*)d_ws;                          // N*64 floats
    int* cnt = (int*)(ft + (size_t)N_NODES * HF);      // N ints
    int* row_ptr = cnt + N_NODES;                      // N+1 ints
    int* cursor = row_ptr + N_NODES + 1;               // N ints
    int* src_grouped = cursor + N_NODES;               // E ints
    int* block_sums = src_grouped + N_EDGES;           // NBLK_SCAN ints

    hipMemsetAsync(cnt, 0, N_NODES * sizeof(int), stream);
    gemm_hist_kernel<<<GEMM_BLOCKS, 256, 0, stream>>>(feat, W, dst, ft, cnt);
    scan1_kernel<<<NBLK_SCAN, 256, 0, stream>>>(cnt, row_ptr, block_sums);
    scan2_kernel<<<1, 256, 0, stream>>>(block_sums);
    scan3_kernel<<<NBLK_SCAN, 256, 0, stream>>>(row_ptr, block_sums, cursor);
    group_kernel<<<(N_EDGES / 4 + 255) / 256, 256, 0, stream>>>(src, dst, cursor, src_grouped);
    gather_kernel<<<N_NODES * 64 / 256, 256, 0, stream>>>(ft, row_ptr, src_grouped, out);
}

// Round 4
// 223.688 us; speedup vs baseline: 1.7704x; 1.0241x over previous
//
#include <hip/hip_runtime.h>

#define N_NODES 50000
#define N_EDGES 800000
#define D_IN 128
#define HH 4
#define FF 16
#define HF 64  // HH*FF
#define NBLK_SCAN ((N_NODES + 255) / 256)  // 196
#define GEMM_BLOCKS ((N_NODES + 63) / 64)  // 782

// ---------------- GEMM: ft[N,64] = feat[N,128] @ W[128,64] ----------------
// 64x64 tile per block, both operands in LDS, 4x4 register micro-tile per
// thread (16 independent FMA chains). As padded to 132 floats/row: row
// stride 132 % 32 = 4 banks -> the 4 distinct row addresses of one a-read
// land on different banks (unpadded 128 -> 4-way conflict).
__global__ __launch_bounds__(256, 2) void gemm_kernel(const float* __restrict__ feat,
                                                      const float* __restrict__ W,
                                                      float* __restrict__ ft) {
    __shared__ float As[64][132];   // ~33.8 KB feat tile (padded)
    __shared__ float Bs[D_IN][HF];  // 32 KB W

    // load W: 2048 float4, coalesced
    {
        const float4* W4 = (const float4*)W;
        float4* B4 = (float4*)Bs;
#pragma unroll
        for (int i = 0; i < 8; ++i) {
            int idx = threadIdx.x + 256 * i;
            B4[idx] = W4[idx];
        }
    }
    // load feat tile: 64 rows x 32 float4
    {
        int row0 = blockIdx.x * 64;
        const float4* F4 = (const float4*)feat;
#pragma unroll
        for (int i = 0; i < 8; ++i) {
            int idx = threadIdx.x + 256 * i;  // [0,2048)
            int r = idx >> 5;
            int c4 = idx & 31;
            float4 v = make_float4(0.f, 0.f, 0.f, 0.f);
            int row = row0 + r;
            if (row < N_NODES) v = F4[(size_t)row * 32 + c4];
            *(float4*)&As[r][c4 * 4] = v;
        }
    }
    __syncthreads();

    const int tr = threadIdx.x >> 4;  // 0..15 -> rows tr*4..tr*4+3
    const int tc = threadIdx.x & 15;  // cols tc*4..tc*4+3

    float acc[4][4] = {};
#pragma unroll 8
    for (int k = 0; k < D_IN; k += 4) {
        float av[4][4], bv[4][4];
#pragma unroll
        for (int i = 0; i < 4; ++i) {
            float4 a = *(const float4*)&As[tr * 4 + i][k];
            av[i][0] = a.x; av[i][1] = a.y; av[i][2] = a.z; av[i][3] = a.w;
        }
#pragma unroll
        for (int j = 0; j < 4; ++j) {
            float4 b = *(const float4*)&Bs[k + j][tc * 4];
            bv[j][0] = b.x; bv[j][1] = b.y; bv[j][2] = b.z; bv[j][3] = b.w;
        }
#pragma unroll
        for (int i = 0; i < 4; ++i)
#pragma unroll
            for (int j = 0; j < 4; ++j)
#pragma unroll
                for (int c = 0; c < 4; ++c)
                    acc[i][c] = fmaf(av[i][j], bv[j][c], acc[i][c]);
    }

    int row0 = blockIdx.x * 64;
#pragma unroll
    for (int i = 0; i < 4; ++i) {
        int row = row0 + tr * 4 + i;
        if (row < N_NODES) {
            *(float4*)&ft[(size_t)row * HF + tc * 4] =
                make_float4(acc[i][0], acc[i][1], acc[i][2], acc[i][3]);
        }
    }
}

// ---------------- histogram of dst (int4 vectorized) ----------------
__global__ __launch_bounds__(256) void hist_kernel(const int* __restrict__ dst,
                                                   int* __restrict__ cnt) {
    int i4 = (blockIdx.x * 256 + threadIdx.x) * 4;
    if (i4 >= N_EDGES) return;  // N_EDGES % 4 == 0
    int4 d4 = *(const int4*)&dst[i4];
    atomicAdd(&cnt[d4.x], 1);
    atomicAdd(&cnt[d4.y], 1);
    atomicAdd(&cnt[d4.z], 1);
    atomicAdd(&cnt[d4.w], 1);
}

// ---------------- scan stage 1: per-256-block exclusive scan ----------------
__global__ __launch_bounds__(256) void scan1_kernel(const int* __restrict__ cnt,
                                                    int* __restrict__ row_ptr,
                                                    int* __restrict__ block_sums) {
    __shared__ int s[256];
    int tid = threadIdx.x;
    int i = blockIdx.x * 256 + tid;
    int val = (i < N_NODES) ? cnt[i] : 0;
    s[tid] = val;
    __syncthreads();
#pragma unroll
    for (int off = 1; off < 256; off <<= 1) {
        int t = (tid >= off) ? s[tid - off] : 0;
        __syncthreads();
        s[tid] += t;
        __syncthreads();
    }
    if (i < N_NODES) row_ptr[i] = s[tid] - val;  // exclusive
    if (tid == 255) block_sums[blockIdx.x] = s[255];
}

// ---------------- scan stage 2: scan the 196 block sums ----------------
__global__ __launch_bounds__(256) void scan2_kernel(int* __restrict__ block_sums) {
    __shared__ int s[256];
    int tid = threadIdx.x;
    int val = (tid < NBLK_SCAN) ? block_sums[tid] : 0;
    s[tid] = val;
    __syncthreads();
#pragma unroll
    for (int off = 1; off < 256; off <<= 1) {
        int t = (tid >= off) ? s[tid - off] : 0;
        __syncthreads();
        s[tid] += t;
        __syncthreads();
    }
    if (tid < NBLK_SCAN) block_sums[tid] = s[tid] - val;  // exclusive
}

// ---------------- scan stage 3: add block offsets; init cursor ----------------
__global__ __launch_bounds__(256) void scan3_kernel(int* __restrict__ row_ptr,
                                                    const int* __restrict__ block_sums,
                                                    int* __restrict__ cursor) {
    int tid = threadIdx.x;
    int i = blockIdx.x * 256 + tid;
    if (i < N_NODES) {
        int v = row_ptr[i] + block_sums[blockIdx.x];
        row_ptr[i] = v;
        cursor[i] = v;
    }
    if (blockIdx.x == 0 && tid == 0) row_ptr[N_NODES] = N_EDGES;
}

// ---------------- group: scatter src ids into dst-grouped order ----------------
__global__ __launch_bounds__(256) void group_kernel(const int* __restrict__ src,
                                                    const int* __restrict__ dst,
                                                    int* __restrict__ cursor,
                                                    int* __restrict__ src_grouped) {
    int i4 = (blockIdx.x * 256 + threadIdx.x) * 4;
    if (i4 >= N_EDGES) return;  // N_EDGES % 4 == 0
    int4 s4 = *(const int4*)&src[i4];
    int4 d4 = *(const int4*)&dst[i4];
    int pos;
    pos = atomicAdd(&cursor[d4.x], 1); src_grouped[pos] = s4.x;
    pos = atomicAdd(&cursor[d4.y], 1); src_grouped[pos] = s4.y;
    pos = atomicAdd(&cursor[d4.z], 1); src_grouped[pos] = s4.z;
    pos = atomicAdd(&cursor[d4.w], 1); src_grouped[pos] = s4.w;
}

// ---------------- fused gather: one wave per destination node ----------------
// lane l <-> (h = l/16, f = l%16). Softmax without max-subtraction (scores
// bounded, exp stays in fp32 range). 8-edge ILP; index loads are wave-uniform
// -> scalar (SMEM) loads, 8 vector gathers in flight.
__global__ __launch_bounds__(256) void gather_kernel(const float* __restrict__ ft,
                                                     const int* __restrict__ row_ptr,
                                                     const int* __restrict__ src_grouped,
                                                     float* __restrict__ out) {
    int node = __builtin_amdgcn_readfirstlane(blockIdx.x * 4 + (threadIdx.x >> 6));
    int lane = threadIdx.x & 63;

    int beg = row_ptr[node];
    int end = row_ptr[node + 1];

    float ftd = ft[(size_t)node * HF + lane];
    float acc = 0.0f, l = 0.0f;

    int i = beg;
    for (; i + 8 <= end; i += 8) {
        int s[8];
        float v[8];
#pragma unroll
        for (int j = 0; j < 8; ++j) s[j] = src_grouped[i + j];
#pragma unroll
        for (int j = 0; j < 8; ++j) v[j] = ft[(size_t)s[j] * HF + lane];
#pragma unroll
        for (int j = 0; j < 8; ++j) {
            float p = ftd * v[j];
            p += __shfl_xor(p, 1, 64);
            p += __shfl_xor(p, 2, 64);
            p += __shfl_xor(p, 4, 64);
            p += __shfl_xor(p, 8, 64);
            float w = __expf(p * 0.25f);
            acc = fmaf(w, v[j], acc);
            l += w;
        }
    }
    for (; i < end; ++i) {
        int s = src_grouped[i];
        float v = ft[(size_t)s * HF + lane];
        float p = ftd * v;
        p += __shfl_xor(p, 1, 64);
        p += __shfl_xor(p, 2, 64);
        p += __shfl_xor(p, 4, 64);
        p += __shfl_xor(p, 8, 64);
        float w = __expf(p * 0.25f);
        acc = fmaf(w, v, acc);
        l += w;
    }

    out[(size_t)node * HF + lane] = (end > beg) ? acc / l : 0.0f;
}

extern "C" void kernel_launch(void* const* d_in, const int* in_sizes, int n_in,
                              void* d_out, int out_size, void* d_ws, size_t ws_size,
                              hipStream_t stream) {
    const float* feat = (const float*)d_in[0];
    const float* W = (const float*)d_in[1];
    const int* src = (const int*)d_in[2];
    const int* dst = (const int*)d_in[3];
    float* out = (float*)d_out;

    // workspace layout
    float* ft = (float*)d_ws;                          // N*64 floats
    int* cnt = (int*)(ft + (size_t)N_NODES * HF);      // N ints
    int* row_ptr = cnt + N_NODES;                      // N+1 ints
    int* cursor = row_ptr + N_NODES + 1;               // N ints
    int* src_grouped = cursor + N_NODES;               // E ints
    int* block_sums = src_grouped + N_EDGES;           // NBLK_SCAN ints

    hipMemsetAsync(cnt, 0, N_NODES * sizeof(int), stream);
    gemm_kernel<<<GEMM_BLOCKS, 256, 0, stream>>>(feat, W, ft);
    hist_kernel<<<(N_EDGES / 4 + 255) / 256, 256, 0, stream>>>(dst, cnt);
    scan1_kernel<<<NBLK_SCAN, 256, 0, stream>>>(cnt, row_ptr, block_sums);
    scan2_kernel<<<1, 256, 0, stream>>>(block_sums);
    scan3_kernel<<<NBLK_SCAN, 256, 0, stream>>>(row_ptr, block_sums, cursor);
    group_kernel<<<(N_EDGES / 4 + 255) / 256, 256, 0, stream>>>(src, dst, cursor, src_grouped);
    gather_kernel<<<N_NODES * 64 / 256, 256, 0, stream>>>(ft, row_ptr, src_grouped, out);
}

// Round 5
// 206.463 us; speedup vs baseline: 1.9181x; 1.0834x over previous
//
#include <hip/hip_runtime.h>

#define N_NODES 50000
#define N_EDGES 800000
#define D_IN 128
#define HH 4
#define FF 16
#define HF 64  // HH*FF
#define NCHAINS 4
#define GEMM_BLOCKS ((N_NODES + 63) / 64)  // 782

// ---------------- GEMM: ft[N,64] = feat[N,128] @ W[128,64] ----------------
// 64x64 tile per block, both operands in LDS, 4x4 register micro-tile per
// thread (16 independent FMA chains). As padded to 132 floats/row.
__global__ __launch_bounds__(256, 2) void gemm_kernel(const float* __restrict__ feat,
                                                      const float* __restrict__ W,
                                                      float* __restrict__ ft) {
    __shared__ float As[64][132];   // ~33.8 KB feat tile (padded)
    __shared__ float Bs[D_IN][HF];  // 32 KB W

    {
        const float4* W4 = (const float4*)W;
        float4* B4 = (float4*)Bs;
#pragma unroll
        for (int i = 0; i < 8; ++i) {
            int idx = threadIdx.x + 256 * i;
            B4[idx] = W4[idx];
        }
    }
    {
        int row0 = blockIdx.x * 64;
        const float4* F4 = (const float4*)feat;
#pragma unroll
        for (int i = 0; i < 8; ++i) {
            int idx = threadIdx.x + 256 * i;  // [0,2048)
            int r = idx >> 5;
            int c4 = idx & 31;
            float4 v = make_float4(0.f, 0.f, 0.f, 0.f);
            int row = row0 + r;
            if (row < N_NODES) v = F4[(size_t)row * 32 + c4];
            *(float4*)&As[r][c4 * 4] = v;
        }
    }
    __syncthreads();

    const int tr = threadIdx.x >> 4;
    const int tc = threadIdx.x & 15;

    float acc[4][4] = {};
#pragma unroll 8
    for (int k = 0; k < D_IN; k += 4) {
        float av[4][4], bv[4][4];
#pragma unroll
        for (int i = 0; i < 4; ++i) {
            float4 a = *(const float4*)&As[tr * 4 + i][k];
            av[i][0] = a.x; av[i][1] = a.y; av[i][2] = a.z; av[i][3] = a.w;
        }
#pragma unroll
        for (int j = 0; j < 4; ++j) {
            float4 b = *(const float4*)&Bs[k + j][tc * 4];
            bv[j][0] = b.x; bv[j][1] = b.y; bv[j][2] = b.z; bv[j][3] = b.w;
        }
#pragma unroll
        for (int i = 0; i < 4; ++i)
#pragma unroll
            for (int j = 0; j < 4; ++j)
#pragma unroll
                for (int c = 0; c < 4; ++c)
                    acc[i][c] = fmaf(av[i][j], bv[j][c], acc[i][c]);
    }

    int row0 = blockIdx.x * 64;
#pragma unroll
    for (int i = 0; i < 4; ++i) {
        int row = row0 + tr * 4 + i;
        if (row < N_NODES) {
            *(float4*)&ft[(size_t)row * HF + tc * 4] =
                make_float4(acc[i][0], acc[i][1], acc[i][2], acc[i][3]);
        }
    }
}

// ---------------- build per-node linked lists (4 chains per node) ----------------
// next2[i] = {next edge id in this chain, src[i]} -- written COALESCED.
// Only the 800 KB head[] takes random atomics (atomicExch, no dependent store).
__global__ __launch_bounds__(256) void build_kernel(const int* __restrict__ src,
                                                    const int* __restrict__ dst,
                                                    int* __restrict__ head,
                                                    int2* __restrict__ next2) {
    int i = blockIdx.x * 256 + threadIdx.x;
    if (i >= N_EDGES) return;
    int d = dst[i];
    int s = src[i];
    int old = atomicExch(&head[d * NCHAINS + (i & (NCHAINS - 1))], i);
    next2[i] = make_int2(old, s);
}

// ---------------- fused gather: one wave per destination node ----------------
// lane l <-> (h = l/16, f = l%16). Walks the node's 4 chains concurrently
// (4-deep ILP on the pointer chase). Softmax without max-subtraction (scores
// bounded: |e| <= |ft_s||ft_d|/4, exp stays in fp32 range). Finished chains
// are predicated to dummy index 0 with weight forced to 0.
__global__ __launch_bounds__(256) void gather_kernel(const float* __restrict__ ft,
                                                     const int* __restrict__ head,
                                                     const int2* __restrict__ next2,
                                                     float* __restrict__ out) {
    int node = __builtin_amdgcn_readfirstlane(blockIdx.x * 4 + (threadIdx.x >> 6));
    int lane = threadIdx.x & 63;

    float ftd = ft[(size_t)node * HF + lane];

    int c0 = head[node * NCHAINS + 0];
    int c1 = head[node * NCHAINS + 1];
    int c2 = head[node * NCHAINS + 2];
    int c3 = head[node * NCHAINS + 3];

    float acc = 0.0f, l = 0.0f;

    // (c0 & c1 & c2 & c3) == -1  iff all chains exhausted (sign bit survives AND
    // only if every value is negative, and the only negative value is -1).
    while ((c0 & c1 & c2 & c3) != -1) {
        bool a0 = c0 >= 0, a1 = c1 >= 0, a2 = c2 >= 0, a3 = c3 >= 0;
        int2 n0 = next2[a0 ? c0 : 0];
        int2 n1 = next2[a1 ? c1 : 0];
        int2 n2 = next2[a2 ? c2 : 0];
        int2 n3 = next2[a3 ? c3 : 0];
        float v0 = ft[(size_t)n0.y * HF + lane];
        float v1 = ft[(size_t)n1.y * HF + lane];
        float v2 = ft[(size_t)n2.y * HF + lane];
        float v3 = ft[(size_t)n3.y * HF + lane];

        float p0 = ftd * v0, p1 = ftd * v1, p2 = ftd * v2, p3 = ftd * v3;
        p0 += __shfl_xor(p0, 1, 64); p1 += __shfl_xor(p1, 1, 64);
        p2 += __shfl_xor(p2, 1, 64); p3 += __shfl_xor(p3, 1, 64);
        p0 += __shfl_xor(p0, 2, 64); p1 += __shfl_xor(p1, 2, 64);
        p2 += __shfl_xor(p2, 2, 64); p3 += __shfl_xor(p3, 2, 64);
        p0 += __shfl_xor(p0, 4, 64); p1 += __shfl_xor(p1, 4, 64);
        p2 += __shfl_xor(p2, 4, 64); p3 += __shfl_xor(p3, 4, 64);
        p0 += __shfl_xor(p0, 8, 64); p1 += __shfl_xor(p1, 8, 64);
        p2 += __shfl_xor(p2, 8, 64); p3 += __shfl_xor(p3, 8, 64);

        float w0 = a0 ? __expf(p0 * 0.25f) : 0.0f;
        float w1 = a1 ? __expf(p1 * 0.25f) : 0.0f;
        float w2 = a2 ? __expf(p2 * 0.25f) : 0.0f;
        float w3 = a3 ? __expf(p3 * 0.25f) : 0.0f;

        acc = fmaf(w0, v0, acc);
        acc = fmaf(w1, v1, acc);
        acc = fmaf(w2, v2, acc);
        acc = fmaf(w3, v3, acc);
        l += (w0 + w1) + (w2 + w3);

        c0 = a0 ? n0.x : -1;
        c1 = a1 ? n1.x : -1;
        c2 = a2 ? n2.x : -1;
        c3 = a3 ? n3.x : -1;
    }

    out[(size_t)node * HF + lane] = (l > 0.0f) ? acc / l : 0.0f;
}

extern "C" void kernel_launch(void* const* d_in, const int* in_sizes, int n_in,
                              void* d_out, int out_size, void* d_ws, size_t ws_size,
                              hipStream_t stream) {
    const float* feat = (const float*)d_in[0];
    const float* W = (const float*)d_in[1];
    const int* src = (const int*)d_in[2];
    const int* dst = (const int*)d_in[3];
    float* out = (float*)d_out;

    // workspace layout
    float* ft = (float*)d_ws;                              // N*64 floats (12.8 MB)
    int* head = (int*)(ft + (size_t)N_NODES * HF);         // N*4 ints   (0.8 MB)
    int2* next2 = (int2*)(head + N_NODES * NCHAINS);       // E int2     (6.4 MB)

    hipMemsetAsync(head, 0xFF, (size_t)N_NODES * NCHAINS * sizeof(int), stream);  // -1
    gemm_kernel<<<GEMM_BLOCKS, 256, 0, stream>>>(feat, W, ft);
    build_kernel<<<(N_EDGES + 255) / 256, 256, 0, stream>>>(src, dst, head, next2);
    gather_kernel<<<N_NODES * 64 / 256, 256, 0, stream>>>(ft, head, next2, out);
}